// Round 18
// baseline (749.568 us; speedup 1.0000x reference)
//
#include <hip/hip_runtime.h>
#include <hip/hip_bf16.h>
#include <cstdint>

typedef __attribute__((ext_vector_type(8))) short bf16x8;
typedef __attribute__((ext_vector_type(4))) float f32x4;

__device__ __forceinline__ unsigned short f2bf_hi(float v) {
    unsigned u = __float_as_uint(v);
    u = u + 0x7fffu + ((u >> 16) & 1u);
    return (unsigned short)(u >> 16);
}
__device__ __forceinline__ float bf2f(unsigned short h) {
    return __uint_as_float(((unsigned)h) << 16);
}

// ---------------------------------------------------------------------------
// scatter: emit bf16 dense directly
__global__ void scatter_kernel(const float* __restrict__ feats,
                               const int* __restrict__ coors,
                               unsigned short* __restrict__ dense,
                               float* __restrict__ mask, int n)
{
    int i = blockIdx.x * blockDim.x + threadIdx.x;
    if (i >= n) return;
    const int z = coors[i * 4 + 1];
    const int y = coors[i * 4 + 2];
    const int x = coors[i * 4 + 3];
    const size_t s = (size_t)((z * 64 + y) * 64 + x);
    dense[s * 3 + 0] = f2bf_hi(feats[i * 3 + 0]);
    dense[s * 3 + 1] = f2bf_hi(feats[i * 3 + 1]);
    dense[s * 3 + 2] = f2bf_hi(feats[i * 3 + 2]);
    mask[s] = 1.f;
}

// ---------------------------------------------------------------------------
// merged weight prep (single-bf16, 5 layers in one launch)
struct Prep5 {
    const float* w[5];
    unsigned short* out[5];
    int ci[5], co[5];
    int start[6];
};
__global__ void wprep_merged(Prep5 P)
{
    const int total = P.start[5];
    const int stride = gridDim.x * blockDim.x;
    for (int g = blockIdx.x * blockDim.x + threadIdx.x; g < total; g += stride) {
        int seg = 0;
        while (g >= P.start[seg + 1]) ++seg;
        const int i = g - P.start[seg];
        const int CI = P.ci[seg], CO = P.co[seg];
        const int tap = i / (CI * CO);
        const int r = i - tap * CI * CO;
        const int ci = r / CO;
        const int co = r - ci * CO;
        const size_t o = ((size_t)(tap * (CI / 8) + (ci >> 3)) * CO + co) * 8 + (ci & 7);
        P.out[seg][o] = f2bf_hi(P.w[seg][i]);
    }
}

// merged weight prep (split hi/lo, 6 deep layers in one launch)
struct Prep6 {
    const float* w[6];
    unsigned short* out[6];
    int ci[6], co[6];
    int start[7];
};
__global__ void wprep2_merged(Prep6 P)
{
    const int total = P.start[6];
    const int stride = gridDim.x * blockDim.x;
    for (int g = blockIdx.x * blockDim.x + threadIdx.x; g < total; g += stride) {
        int seg = 0;
        while (g >= P.start[seg + 1]) ++seg;
        const int i = g - P.start[seg];
        const int CI = P.ci[seg], CO = P.co[seg];
        const int tap = i / (CI * CO);
        const int r = i - tap * CI * CO;
        const int ci = r / CO;
        const int co = r - ci * CO;
        const float v = P.w[seg][i];
        const unsigned short h = f2bf_hi(v);
        const unsigned short l = f2bf_hi(v - bf2f(h));
        const size_t o = ((size_t)(tap * (CI / 8) + (ci >> 3)) * CO + co) * 16 + (ci & 7);
        P.out[seg][o] = h; P.out[seg][o + 8] = l;
    }
}

// conv1 weights: [75][3][64] fp32 -> K=256-padded split hi/lo
__global__ void wprep1_kernel(const float* __restrict__ w,
                              unsigned short* __restrict__ wv1)
{
    const int i = blockIdx.x * blockDim.x + threadIdx.x;
    if (i >= 256 * 64) return;
    const int k = i >> 6, co = i & 63;
    unsigned short h = 0, l = 0;
    if (k < 225) {
        const float v = w[k * 64 + co];
        h = f2bf_hi(v);
        l = f2bf_hi(v - bf2f(h));
    }
    const size_t o = (size_t)(k >> 3) * 1024 + co * 16 + (k & 7);
    wv1[o] = h; wv1[o + 8] = l;
}

// ---------------------------------------------------------------------------
// L0 conv1 via MFMA: per (z,y) row GEMM  M=64(x) x N=64(co) x K=225(pad 256).
__global__ __launch_bounds__(256)
void conv1m_kernel(const unsigned short* __restrict__ in,
                   const unsigned short* __restrict__ wv1,
                   const float* __restrict__ mask, unsigned short* __restrict__ ob)
{
    constexpr int S = 64;
    constexpr int RW = 204;
    constexpr int RP = 208;
    __shared__ unsigned short lds[15 * RP];

    const int bid = blockIdx.y * S + blockIdx.x;
    const int wg = (bid & 7) * (S * S / 8) + (bid >> 3);
    const int y = wg & 63, z = wg >> 6;
    const int t = threadIdx.x;

    for (int idx = t; idx < 15 * RW; idx += 256) {
        const int r = idx / RW;
        const int q = idx - r * RW;
        const int xp = q / 3, ci = q - xp * 3;
        const int kz = r / 5, ky = r - kz * 5;
        const int zz = z + kz - 1, yy = y + ky - 2, xi = xp - 2;
        unsigned short v = 0;
        if ((unsigned)zz < (unsigned)S && (unsigned)yy < (unsigned)S && (unsigned)xi < (unsigned)S)
            v = in[(size_t)((zz * S + yy) * S + xi) * 3 + ci];
        lds[r * RP + q] = v;
    }
    __syncthreads();

    const int lane = t & 63;
    const int xf = t >> 6;
    const int col = lane & 15;
    const int ci8 = lane >> 4;

    f32x4 acc[4];
    const f32x4 vzero = {0.f, 0.f, 0.f, 0.f};
#pragma unroll
    for (int n = 0; n < 4; ++n) acc[n] = vzero;

    const int abase = (xf * 16 + col) * 3;

#pragma unroll
    for (int kc = 0; kc < 8; ++kc) {
        unsigned short av[8];
#pragma unroll
        for (int e = 0; e < 8; ++e) {
            int k = kc * 32 + ci8 * 8 + e;
            if (k > 224) k = 224;
            const int tap = k / 3, ci = k - 3 * tap;
            const int kzy = tap / 5, kx = tap - kzy * 5;
            av[e] = lds[kzy * RP + abase + kx * 3 + ci];
        }
        bf16x8 a;
#pragma unroll
        for (int e = 0; e < 8; ++e) ((unsigned short*)&a)[e] = av[e];

#pragma unroll
        for (int n = 0; n < 4; ++n) {
            const unsigned short* wp = wv1 + (size_t)(kc * 4 + ci8) * 1024 + (n * 16 + col) * 16;
            bf16x8 wh = *(const bf16x8*)wp;
            bf16x8 wl = *(const bf16x8*)(wp + 8);
            acc[n] = __builtin_amdgcn_mfma_f32_16x16x32_bf16(a, wh, acc[n], 0, 0, 0);
            acc[n] = __builtin_amdgcn_mfma_f32_16x16x32_bf16(a, wl, acc[n], 0, 0, 0);
        }
    }

    const int rq = lane >> 4;
    const size_t vb = (size_t)(z * S + y) * S;
#pragma unroll
    for (int r = 0; r < 4; ++r) {
        const int x = xf * 16 + rq * 4 + r;
        const float keep = (mask[vb + x] > 0.f) ? 1.f : 0.f;
#pragma unroll
        for (int n = 0; n < 4; ++n) {
            const int co = n * 16 + col;
            ob[(vb + x) * 64 + co] = f2bf_hi(acc[n][r] * keep);
        }
    }
}

// ---------------------------------------------------------------------------
// MFMA conv v7 (L0c2): YB rows/block, two rows staged per phase.
template<int CIN, int COUT, int S, int YB, int YG, int WN, int NG, int OMODE>
__global__ __launch_bounds__(YG * NG * 64)
void mfma_conv7(const unsigned short* __restrict__ ab,
                const unsigned short* __restrict__ wv,
                const float* __restrict__ mask, float* __restrict__ outf,
                unsigned short* __restrict__ outb)
{
    constexpr int SP = S + 4;
    constexpr int MX = S / 16;
    constexpr int KC = CIN / 32;
    constexpr int KC4 = CIN / 8;
    constexpr int RS = (KC4 <= 8) ? 8 : 16;
    constexpr int PLANE = SP * RS;
    constexpr int NLR = SP * KC4;
    constexpr int NL = 2 * NLR;
    constexpr int NW = YG * NG;
    constexpr int NT = NW * 64;
    constexpr int SREG = (NL + NT - 1) / NT;
    constexpr int YBW = YB / YG;
    constexpr int NYB = S / YB;
    constexpr int JP = (YB + 4) / 2;
    constexpr int NP = 3 * JP;
    static_assert(COUT / 16 == WN * NG, "geometry");
    static_assert((YB + 4) % 2 == 0, "YB even");

    __shared__ unsigned short lds[2 * 2 * PLANE * 8];

    const int bid = blockIdx.y * NYB + blockIdx.x;
    constexpr int NWG = NYB * S;
    const int wg = (bid & 7) * (NWG / 8) + (bid >> 3);
    const int yb = wg % NYB, z = wg / NYB;
    const int y0 = yb * YB;

    const int t = threadIdx.x;
    const int lane = t & 63;
    const int wave = t >> 6;
    const int waveN = wave % NG;
    const int waveY = wave / NG;
    const int col = lane & 15;
    const int ci8 = lane >> 4;

    f32x4 acc[YBW][MX][WN];
    const f32x4 vzero = {0.f, 0.f, 0.f, 0.f};
#pragma unroll
    for (int q = 0; q < YBW; ++q)
#pragma unroll
        for (int m = 0; m < MX; ++m)
#pragma unroll
            for (int n = 0; n < WN; ++n) acc[q][m][n] = vzero;

    uint4 reg[SREG];

    auto issue = [&](int ph) {
        const int kz = ph / JP, jp = ph - kz * JP;
        const int zz = z + kz - 1;
        const bool zv = ((unsigned)zz < (unsigned)S);
#pragma unroll
        for (int i = 0; i < SREG; ++i) {
            const int L = i * NT + t;
            uint4 v = {0u, 0u, 0u, 0u};
            if (L < NL) {
                const int jr = L / NLR;
                const int l2 = L - jr * NLR;
                const int x = l2 / KC4;
                const int c3 = l2 - x * KC4;
                const int xi = x - 2;
                const int yy = y0 + jp * 2 + jr - 2;
                if (zv && (unsigned)yy < (unsigned)S && (unsigned)xi < (unsigned)S)
                    v = *(const uint4*)(ab + (size_t)((zz * S + yy) * S + xi) * CIN + c3 * 8);
            }
            reg[i] = v;
        }
    };
    auto store = [&](int pl) {
#pragma unroll
        for (int i = 0; i < SREG; ++i) {
            const int L = i * NT + t;
            if (L < NL) {
                const int jr = L / NLR;
                const int l2 = L - jr * NLR;
                const int x = l2 / KC4;
                const int c3 = l2 - x * KC4;
                const int p = x * RS + (c3 ^ (x & 7));
                *(uint4*)&lds[((pl * 2 + jr) * PLANE + p) * 8] = reg[i];
            }
        }
    };

    issue(0);
    store(0);
    if (NP > 1) issue(1);
    __syncthreads();

    int cur = 0;
#pragma unroll 1
    for (int ph = 0; ph < NP; ++ph) {
        const int kz = ph / JP, jp = ph - kz * JP;
        const int zz = z + kz - 1;
        if ((unsigned)zz < (unsigned)S) {
#pragma unroll
            for (int jr = 0; jr < 2; ++jr) {
                const int j = jp * 2 + jr;
                const int yy = y0 + j - 2;
                if ((unsigned)yy >= (unsigned)S) continue;
                const unsigned short* plane = lds + (cur * 2 + jr) * PLANE * 8;

                bool vq[YBW];
                int tapb[YBW];
#pragma unroll
                for (int ql = 0; ql < YBW; ++ql) {
                    const int q = waveY * YBW + ql;
                    const int ky = j - q;
                    vq[ql] = (ky >= 0 && ky <= 4);
                    tapb[ql] = (kz * 5 + (vq[ql] ? ky : 0)) * 5;
                }

                bf16x8 wA[YBW][KC][WN], wB[YBW][KC][WN];
                auto wload = [&](bf16x8 (&wb)[YBW][KC][WN], int kx) {
#pragma unroll
                    for (int ql = 0; ql < YBW; ++ql) if (vq[ql]) {
                        const int tap = tapb[ql] + kx;
#pragma unroll
                        for (int kc = 0; kc < KC; ++kc) {
                            const int c3 = kc * 4 + ci8;
#pragma unroll
                            for (int n = 0; n < WN; ++n) {
                                const int co = (waveN * WN + n) * 16 + col;
                                wb[ql][kc][n] = *(const bf16x8*)(wv + ((size_t)(tap * KC4 + c3) * COUT + co) * 8);
                            }
                        }
                    }
                };
                auto wmfma = [&](bf16x8 (&wb)[YBW][KC][WN], bf16x8 (&a)[KC][MX]) {
#pragma unroll
                    for (int ql = 0; ql < YBW; ++ql) if (vq[ql])
#pragma unroll
                        for (int kc = 0; kc < KC; ++kc)
#pragma unroll
                            for (int m = 0; m < MX; ++m)
#pragma unroll
                                for (int n = 0; n < WN; ++n)
                                    acc[ql][m][n] = __builtin_amdgcn_mfma_f32_16x16x32_bf16(a[kc][m], wb[ql][kc][n], acc[ql][m][n], 0, 0, 0);
                };

                wload(wA, 0);
                __builtin_amdgcn_s_setprio(1);
#pragma unroll
                for (int kx = 0; kx < 5; ++kx) {
                    bf16x8 a[KC][MX];
#pragma unroll
                    for (int kc = 0; kc < KC; ++kc) {
                        const int c3 = kc * 4 + ci8;
#pragma unroll
                        for (int m = 0; m < MX; ++m) {
                            const int x = m * 16 + col + kx;
                            const int p = x * RS + (c3 ^ (x & 7));
                            a[kc][m] = *(const bf16x8*)&plane[p * 8];
                        }
                    }
                    if ((kx & 1) == 0) {
                        if (kx + 1 < 5) wload(wB, kx + 1);
                        wmfma(wA, a);
                    } else {
                        if (kx + 1 < 5) wload(wA, kx + 1);
                        wmfma(wB, a);
                    }
                }
                __builtin_amdgcn_s_setprio(0);
            }
        }
        if (ph + 1 < NP) store(cur ^ 1);
        if (ph + 2 < NP) issue(ph + 2);
        __syncthreads();
        cur ^= 1;
    }

    const int rq = lane >> 4;
#pragma unroll
    for (int ql = 0; ql < YBW; ++ql) {
        const int y = y0 + waveY * YBW + ql;
        const size_t vb = (size_t)(z * S + y) * S;
#pragma unroll
        for (int m = 0; m < MX; ++m) {
            const int xb = m * 16 + rq * 4;
#pragma unroll
            for (int r = 0; r < 4; ++r) {
                const int x = xb + r;
                const float keep = (mask[vb + x] > 0.f) ? 1.f : 0.f;
#pragma unroll
                for (int n = 0; n < WN; ++n) {
                    const int co = (waveN * WN + n) * 16 + col;
                    const float v = acc[ql][m][n][r] * keep;
                    if (OMODE == 0) outf[(vb + x) * COUT + co] = v;
                    else            outb[(vb + x) * COUT + co] = f2bf_hi(v);
                }
            }
        }
    }
}

// ---------------------------------------------------------------------------
// MFMA conv v6 (L1): YB rows/block, one row per phase.
template<int CIN, int COUT, int S, int YB, int YG, int WN, int NG, int OMODE>
__global__ __launch_bounds__(YG * NG * 64)
void mfma_conv6(const unsigned short* __restrict__ ab,
                const unsigned short* __restrict__ wv,
                const float* __restrict__ mask, float* __restrict__ outf,
                unsigned short* __restrict__ outb)
{
    constexpr int SP = S + 4;
    constexpr int MX = S / 16;
    constexpr int KC = CIN / 32;
    constexpr int KC4 = CIN / 8;
    constexpr int RS = (KC4 <= 8) ? 8 : 16;
    constexpr int PLANE = SP * RS;
    constexpr int NL = SP * KC4;
    constexpr int NW = YG * NG;
    constexpr int NT = NW * 64;
    constexpr int SREG = (NL + NT - 1) / NT;
    constexpr int YBW = YB / YG;
    constexpr int NYB = S / YB;
    constexpr int NP = 3 * (YB + 4);
    static_assert(COUT / 16 == WN * NG, "geometry");

    __shared__ unsigned short lds[2 * PLANE * 8];

    const int bid = blockIdx.y * NYB + blockIdx.x;
    constexpr int NWG = NYB * S;
    const int wg = (bid & 7) * (NWG / 8) + (bid >> 3);
    const int yb = wg % NYB, z = wg / NYB;
    const int y0 = yb * YB;

    const int t = threadIdx.x;
    const int lane = t & 63;
    const int wave = t >> 6;
    const int waveN = wave % NG;
    const int waveY = wave / NG;
    const int col = lane & 15;
    const int ci8 = lane >> 4;

    f32x4 acc[YBW][MX][WN];
    const f32x4 vzero = {0.f, 0.f, 0.f, 0.f};
#pragma unroll
    for (int q = 0; q < YBW; ++q)
#pragma unroll
        for (int m = 0; m < MX; ++m)
#pragma unroll
            for (int n = 0; n < WN; ++n) acc[q][m][n] = vzero;

    uint4 reg[SREG];

    auto issue = [&](int ph) {
        const int kz = ph / (YB + 4), j = ph - kz * (YB + 4);
        const int zz = z + kz - 1, yy = y0 + j - 2;
        const bool rv = ((unsigned)zz < (unsigned)S) && ((unsigned)yy < (unsigned)S);
        const size_t rowbase = rv ? (size_t)((zz * S + yy) * S) * CIN : 0;
#pragma unroll
        for (int i = 0; i < SREG; ++i) {
            const int L = i * NT + t;
            uint4 v = {0u, 0u, 0u, 0u};
            if (L < NL) {
                const int x = L / KC4;
                const int c3 = L - x * KC4;
                const int xi = x - 2;
                if (rv && (unsigned)xi < (unsigned)S)
                    v = *(const uint4*)(ab + rowbase + (size_t)xi * CIN + c3 * 8);
            }
            reg[i] = v;
        }
    };
    auto store = [&](int pl) {
#pragma unroll
        for (int i = 0; i < SREG; ++i) {
            const int L = i * NT + t;
            if (L < NL) {
                const int x = L / KC4;
                const int c3 = L - x * KC4;
                const int p = x * RS + (c3 ^ (x & 7));
                *(uint4*)&lds[(pl * PLANE + p) * 8] = reg[i];
            }
        }
    };

    issue(0);
    store(0);
    if (NP > 1) issue(1);
    __syncthreads();

    int cur = 0;
#pragma unroll 1
    for (int ph = 0; ph < NP; ++ph) {
        const int kz = ph / (YB + 4), j = ph - kz * (YB + 4);
        const int zz = z + kz - 1, yy = y0 + j - 2;
        if (((unsigned)zz < (unsigned)S) && ((unsigned)yy < (unsigned)S)) {
            const unsigned short* plane = lds + cur * PLANE * 8;

            bool vq[YBW];
            int tapb[YBW];
#pragma unroll
            for (int ql = 0; ql < YBW; ++ql) {
                const int q = waveY * YBW + ql;
                const int ky = j - q;
                vq[ql] = (ky >= 0 && ky <= 4);
                tapb[ql] = (kz * 5 + (vq[ql] ? ky : 0)) * 5;
            }

            bf16x8 wA[YBW][KC][WN], wB[YBW][KC][WN];
            auto wload = [&](bf16x8 (&wb)[YBW][KC][WN], int kx) {
#pragma unroll
                for (int ql = 0; ql < YBW; ++ql) if (vq[ql]) {
                    const int tap = tapb[ql] + kx;
#pragma unroll
                    for (int kc = 0; kc < KC; ++kc) {
                        const int c3 = kc * 4 + ci8;
#pragma unroll
                        for (int n = 0; n < WN; ++n) {
                            const int co = (waveN * WN + n) * 16 + col;
                            wb[ql][kc][n] = *(const bf16x8*)(wv + ((size_t)(tap * KC4 + c3) * COUT + co) * 8);
                        }
                    }
                }
            };
            auto wmfma = [&](bf16x8 (&wb)[YBW][KC][WN], bf16x8 (&a)[KC][MX]) {
#pragma unroll
                for (int ql = 0; ql < YBW; ++ql) if (vq[ql])
#pragma unroll
                    for (int kc = 0; kc < KC; ++kc)
#pragma unroll
                        for (int m = 0; m < MX; ++m)
#pragma unroll
                            for (int n = 0; n < WN; ++n)
                                acc[ql][m][n] = __builtin_amdgcn_mfma_f32_16x16x32_bf16(a[kc][m], wb[ql][kc][n], acc[ql][m][n], 0, 0, 0);
            };

            wload(wA, 0);
            __builtin_amdgcn_s_setprio(1);
#pragma unroll
            for (int kx = 0; kx < 5; ++kx) {
                bf16x8 a[KC][MX];
#pragma unroll
                for (int kc = 0; kc < KC; ++kc) {
                    const int c3 = kc * 4 + ci8;
#pragma unroll
                    for (int m = 0; m < MX; ++m) {
                        const int x = m * 16 + col + kx;
                        const int p = x * RS + (c3 ^ (x & 7));
                        a[kc][m] = *(const bf16x8*)&plane[p * 8];
                    }
                }
                if ((kx & 1) == 0) {
                    if (kx + 1 < 5) wload(wB, kx + 1);
                    wmfma(wA, a);
                } else {
                    if (kx + 1 < 5) wload(wA, kx + 1);
                    wmfma(wB, a);
                }
            }
            __builtin_amdgcn_s_setprio(0);
        }
        if (ph + 1 < NP) store(cur ^ 1);
        if (ph + 2 < NP) issue(ph + 2);
        __syncthreads();
        cur ^= 1;
    }

    const int rq = lane >> 4;
#pragma unroll
    for (int ql = 0; ql < YBW; ++ql) {
        const int y = y0 + waveY * YBW + ql;
        const size_t vb = (size_t)(z * S + y) * S;
#pragma unroll
        for (int m = 0; m < MX; ++m) {
            const int xb = m * 16 + rq * 4;
#pragma unroll
            for (int r = 0; r < 4; ++r) {
                const int x = xb + r;
                const float keep = (mask[vb + x] > 0.f) ? 1.f : 0.f;
#pragma unroll
                for (int n = 0; n < WN; ++n) {
                    const int co = (waveN * WN + n) * 16 + col;
                    const float v = acc[ql][m][n][r] * keep;
                    if (OMODE == 0) outf[(vb + x) * COUT + co] = v;
                    else            outb[(vb + x) * COUT + co] = f2bf_hi(v);
                }
            }
        }
    }
}

// ---------------------------------------------------------------------------
// MFMA conv v3c (L2): single-bf16 weights, LDS double-buffer, kx pipelining.
template<int CIN, int COUT, int S, int WM, int WN, int MG, int NG, int OMODE>
__global__ __launch_bounds__(MG * NG * 64)
void mfma_conv3c(const unsigned short* __restrict__ ab,
                 const unsigned short* __restrict__ wv,
                 const float* __restrict__ mask, float* __restrict__ outf,
                 unsigned short* __restrict__ outb)
{
    constexpr int SP = S + 4;
    constexpr int KC = CIN / 32;
    constexpr int KC4 = CIN / 8;
    constexpr int RS = (KC4 <= 8) ? 8 : 16;
    constexpr int PLANE = SP * RS;
    constexpr int NL = SP * KC4;
    constexpr int NT = MG * NG * 64;
    constexpr int SREG = (NL + NT - 1) / NT;
    static_assert(S / 16 == WM * MG && COUT / 16 == WN * NG, "geometry");

    __shared__ unsigned short lds[2 * PLANE * 8];

    const int bid = blockIdx.y * S + blockIdx.x;
    const int wg = (bid & 7) * (S * S / 8) + (bid >> 3);
    const int y = wg % S, z = wg / S;

    const int t = threadIdx.x;
    const int lane = t & 63;
    const int wave = t >> 6;
    const int waveM = wave % MG;
    const int waveN = wave / MG;
    const int col = lane & 15;
    const int ci8 = lane >> 4;

    f32x4 acc[WM][WN];
    const f32x4 vzero = {0.f, 0.f, 0.f, 0.f};
#pragma unroll
    for (int m = 0; m < WM; ++m)
#pragma unroll
        for (int n = 0; n < WN; ++n) acc[m][n] = vzero;

    uint4 reg[SREG];

    auto issue = [&](int kzy) {
        const int kz = kzy / 5, ky = kzy - kz * 5;
        const int zz = z + kz - 1, yy = y + ky - 2;
        const bool rv = ((unsigned)zz < (unsigned)S) && ((unsigned)yy < (unsigned)S);
        const size_t rowbase = rv ? (size_t)((zz * S + yy) * S) * CIN : 0;
#pragma unroll
        for (int i = 0; i < SREG; ++i) {
            const int L = i * NT + t;
            uint4 v = {0u, 0u, 0u, 0u};
            if (L < NL) {
                const int x = L / KC4;
                const int c3 = L - x * KC4;
                const int xi = x - 2;
                if (rv && (unsigned)xi < (unsigned)S)
                    v = *(const uint4*)(ab + rowbase + (size_t)xi * CIN + c3 * 8);
            }
            reg[i] = v;
        }
    };
    auto store = [&](int pl) {
#pragma unroll
        for (int i = 0; i < SREG; ++i) {
            const int L = i * NT + t;
            if (L < NL) {
                const int x = L / KC4;
                const int c3 = L - x * KC4;
                const int p = x * RS + (c3 ^ (x & 7));
                *(uint4*)&lds[(pl * PLANE + p) * 8] = reg[i];
            }
        }
    };

    issue(0);
    store(0);
    issue(1);
    __syncthreads();

    int cur = 0;
#pragma unroll 1
    for (int kzy = 0; kzy < 15; ++kzy) {
        const int kz = kzy / 5, ky = kzy - kz * 5;
        const int zz = z + kz - 1, yy = y + ky - 2;
        if (((unsigned)zz < (unsigned)S) && ((unsigned)yy < (unsigned)S)) {
            const unsigned short* plane = lds + cur * PLANE * 8;

            bf16x8 wA[KC][WN], wB[KC][WN];
            auto wload = [&](bf16x8 (&wb)[KC][WN], int kx) {
                const int tap = kzy * 5 + kx;
#pragma unroll
                for (int kc = 0; kc < KC; ++kc) {
                    const int c3 = kc * 4 + ci8;
#pragma unroll
                    for (int n = 0; n < WN; ++n) {
                        const int co = (waveN * WN + n) * 16 + col;
                        wb[kc][n] = *(const bf16x8*)(wv + ((size_t)(tap * KC4 + c3) * COUT + co) * 8);
                    }
                }
            };
            auto wmfma = [&](bf16x8 (&wb)[KC][WN], bf16x8 (&a)[KC][WM]) {
#pragma unroll
                for (int kc = 0; kc < KC; ++kc)
#pragma unroll
                    for (int m = 0; m < WM; ++m)
#pragma unroll
                        for (int n = 0; n < WN; ++n)
                            acc[m][n] = __builtin_amdgcn_mfma_f32_16x16x32_bf16(a[kc][m], wb[kc][n], acc[m][n], 0, 0, 0);
            };

            wload(wA, 0);
            __builtin_amdgcn_s_setprio(1);
#pragma unroll
            for (int kx = 0; kx < 5; ++kx) {
                bf16x8 a[KC][WM];
#pragma unroll
                for (int kc = 0; kc < KC; ++kc) {
                    const int c3 = kc * 4 + ci8;
#pragma unroll
                    for (int m = 0; m < WM; ++m) {
                        const int x = (waveM * WM + m) * 16 + col + kx;
                        const int p = x * RS + (c3 ^ (x & 7));
                        a[kc][m] = *(const bf16x8*)&plane[p * 8];
                    }
                }
                if ((kx & 1) == 0) {
                    if (kx + 1 < 5) wload(wB, kx + 1);
                    wmfma(wA, a);
                } else {
                    if (kx + 1 < 5) wload(wA, kx + 1);
                    wmfma(wB, a);
                }
            }
            __builtin_amdgcn_s_setprio(0);
        }
        if (kzy + 1 < 15) store(cur ^ 1);
        if (kzy + 2 < 15) issue(kzy + 2);
        __syncthreads();
        cur ^= 1;
    }

    const int rq = lane >> 4;
    const size_t vb = (size_t)(z * S + y) * S;
#pragma unroll
    for (int m = 0; m < WM; ++m) {
        const int xb = (waveM * WM + m) * 16 + rq * 4;
#pragma unroll
        for (int r = 0; r < 4; ++r) {
            const int x = xb + r;
            const float keep = (mask[vb + x] > 0.f) ? 1.f : 0.f;
#pragma unroll
            for (int n = 0; n < WN; ++n) {
                const int co = (waveN * WN + n) * 16 + col;
                const float v = acc[m][n][r] * keep;
                if (OMODE == 0) outf[(vb + x) * COUT + co] = v;
                else            outb[(vb + x) * COUT + co] = f2bf_hi(v);
            }
        }
    }
}

// ---------------------------------------------------------------------------
// Deep-level conv as flat implicit GEMM v2: NW waves split the 75 taps.
template<int CIN, int COUT, int S, int NW>
__global__ __launch_bounds__(NW * 64)
void dgemm2_kernel(const unsigned short* __restrict__ inb,
                   const unsigned short* __restrict__ wv,
                   const float* __restrict__ mask,
                   unsigned short* __restrict__ outb)
{
    constexpr int M = S * S * S;
    constexpr int KC = CIN / 32;
    constexpr int KC4 = CIN / 8;
    __shared__ f32x4 part[NW][64];

    const int t = threadIdx.x;
    const int lane = t & 63;
    const int w = t >> 6;
    const int col = lane & 15;
    const int g = lane >> 4;

    const int va = blockIdx.x * 16 + col;
    const bool av = (va < M);
    const int az = (va / (S * S)) % S;
    const int ay = (va / S) % S;
    const int ax = va % S;
    const int co = blockIdx.y * 16 + col;

    f32x4 acc0 = {0.f, 0.f, 0.f, 0.f};
    f32x4 acc1 = {0.f, 0.f, 0.f, 0.f};

#pragma unroll 2
    for (int tap = w; tap < 75; tap += NW) {
        const int dz = tap / 25 - 1;
        const int dy = (tap / 5) % 5 - 2;
        const int dx = tap % 5 - 2;
        const int zz = az + dz, yy = ay + dy, xx = ax + dx;
        const bool valid = av && ((unsigned)zz < (unsigned)S) &&
                           ((unsigned)yy < (unsigned)S) && ((unsigned)xx < (unsigned)S);
        const size_t abase = valid ? (size_t)((zz * S + yy) * S + xx) * CIN : 0;
#pragma unroll
        for (int kc = 0; kc < KC; ++kc) {
            const int c3 = kc * 4 + g;
            bf16x8 a = {0, 0, 0, 0, 0, 0, 0, 0};
            if (valid) a = *(const bf16x8*)(inb + abase + c3 * 8);
            const unsigned short* wp = wv + ((size_t)(tap * KC4 + c3) * COUT + co) * 16;
            bf16x8 wh = *(const bf16x8*)wp;
            bf16x8 wl = *(const bf16x8*)(wp + 8);
            acc0 = __builtin_amdgcn_mfma_f32_16x16x32_bf16(a, wh, acc0, 0, 0, 0);
            acc1 = __builtin_amdgcn_mfma_f32_16x16x32_bf16(a, wl, acc1, 0, 0, 0);
        }
    }

    part[w][lane] = acc0 + acc1;
    __syncthreads();

    if (w == 0) {
        f32x4 s = part[0][lane];
#pragma unroll
        for (int i = 1; i < NW; ++i) s += part[i][lane];
#pragma unroll
        for (int r = 0; r < 4; ++r) {
            const int v = blockIdx.x * 16 + g * 4 + r;
            if (v < M) {
                const float keep = (mask[v] > 0.f) ? 1.f : 0.f;
                outb[(size_t)v * COUT + co] = f2bf_hi(s[r] * keep);
            }
        }
    }
}

// ---------------------------------------------------------------------------
// bf16 pool, vectorized: 8 channels per thread.
__global__ void pool_bf8_kernel(const unsigned short* __restrict__ inb,
                                const float* __restrict__ mi,
                                unsigned short* __restrict__ outb,
                                float* __restrict__ mo, int S, int C)
{
    const int So = S >> 1;
    const int C8 = C >> 3;
    const long long total = (long long)So * So * So * C8;
    for (long long i = blockIdx.x * (long long)blockDim.x + threadIdx.x; i < total;
         i += (long long)gridDim.x * blockDim.x) {
        const int c8 = (int)(i % C8);
        const long long s = i / C8;
        const int xo = (int)(s % So);
        const int yo = (int)((s / So) % So);
        const int zo = (int)(s / ((long long)So * So));
        float best[8];
#pragma unroll
        for (int k = 0; k < 8; ++k) best[k] = -1e30f;
        float m2 = 0.f;
        for (int dz = 0; dz < 2; ++dz)
            for (int dy = 0; dy < 2; ++dy)
                for (int dx = 0; dx < 2; ++dx) {
                    const int zi = zo * 2 + dz, yi = yo * 2 + dy, xi = xo * 2 + dx;
                    const float m = mi[(zi * S + yi) * S + xi];
                    if (m > 0.f) {
                        m2 = 1.f;
                        const unsigned short* p =
                            inb + ((size_t)((zi * S + yi) * S + xi) * C8 + c8) * 8;
                        uint4 v = *(const uint4*)p;
                        const unsigned short* vs = (const unsigned short*)&v;
#pragma unroll
                        for (int k = 0; k < 8; ++k) best[k] = fmaxf(best[k], bf2f(vs[k]));
                    }
                }
        uint4 o;
        unsigned short* os = (unsigned short*)&o;
#pragma unroll
        for (int k = 0; k < 8; ++k) os[k] = f2bf_hi((m2 > 0.f) ? best[k] : 0.f);
        *(uint4*)(outb + i * 8) = o;
        if (c8 == 0) mo[s] = m2;
    }
}

__global__ __launch_bounds__(256)
void final_kernel(const unsigned short* __restrict__ h, const float* __restrict__ mask,
                  const float* __restrict__ w12, const float* __restrict__ w13,
                  float* __restrict__ out)
{
    __shared__ float o1[256];
    const int co = threadIdx.x;
    const float m = (mask[0] > 0.f) ? 1.f : 0.f;
    float a = 0.f;
    for (int ci = 0; ci < 224; ++ci)
        a += bf2f(h[ci]) * w12[(size_t)(37 * 224 + ci) * 256 + co];
    o1[co] = a * m;
    __syncthreads();
    float b = 0.f;
    for (int ci = 0; ci < 256; ++ci)
        b += o1[ci] * w13[(size_t)(37 * 256 + ci) * 256 + co];
    out[co] = b * m;
}

static void pool_bf8(const unsigned short* inb, const float* mi,
                     unsigned short* outb, float* mo, int S, int C, hipStream_t stream)
{
    const long long total = (long long)(S / 2) * (S / 2) * (S / 2) * (C / 8);
    long long grid = (total + 255) / 256;
    if (grid > 4096) grid = 4096;
    if (grid < 1) grid = 1;
    pool_bf8_kernel<<<(int)grid, 256, 0, stream>>>(inb, mi, outb, mo, S, C);
}

// weight-pool element offsets (shorts, hi-only): L0c2, L1c1, L1c2, L2c1, L2c2
#define WOFF0 0
#define WOFF1 307200
#define WOFF2 768000
#define WOFF3 1459200
#define WOFF4 2380800
// deep split-weight offsets (shorts, hi+lo): L3c1..L5c2
#define DOFF6 0
#define DOFF7 3072000
#define DOFF8 6912000
#define DOFF9 11520000
#define DOFF10 17049600
#define DOFF11 23500800

extern "C" void kernel_launch(void* const* d_in, const int* in_sizes, int n_in,
                              void* d_out, int out_size, void* d_ws, size_t ws_size,
                              hipStream_t stream)
{
    const float* feats = (const float*)d_in[0];
    const int*   coors = (const int*)d_in[1];
    const float* w[14];
    for (int i = 0; i < 14; ++i) w[i] = (const float*)d_in[3 + i];
    float* outp = (float*)d_out;

    // ws layout
    unsigned short* dense0 = (unsigned short*)d_ws;        // bf16, 786432 shorts
    float* mA = (float*)d_ws + 786432;                     // 262144
    float* mB = mA + 262144;                               // 262144
    unsigned short* ab = (unsigned short*)(mB + 262144);   // 16.7M shorts
    unsigned short* bb = ab + 16777216;                    // 16.7M shorts
    unsigned short* wvp = bb + 16777216;                   // 3.6M shorts (L0-L2)
    unsigned short* wdp = wvp + 3609600;                   // 31.1M shorts (deep)
    unsigned short* wv1 = wdp + 31104000;                  // 32768 shorts (conv1)

    const int npts = in_sizes[0] / 3;

    // ---- weight prep: 3 launches total ----
    wprep1_kernel<<<64, 256, 0, stream>>>(w[0], wv1);

    Prep5 p5;
    {
        const int ci[5] = {64, 64, 96, 96, 128};
        const int co[5] = {64, 96, 96, 128, 128};
        const int off[5] = {WOFF0, WOFF1, WOFF2, WOFF3, WOFF4};
        int acc = 0;
        for (int s = 0; s < 5; ++s) {
            p5.w[s] = w[1 + s];
            p5.out[s] = wvp + off[s];
            p5.ci[s] = ci[s]; p5.co[s] = co[s];
            p5.start[s] = acc;
            acc += 75 * ci[s] * co[s];
        }
        p5.start[5] = acc;
    }
    wprep_merged<<<2048, 256, 0, stream>>>(p5);

    Prep6 p6;
    {
        const int ci[6] = {128, 160, 160, 192, 192, 224};
        const int co[6] = {160, 160, 192, 192, 224, 224};
        const int off[6] = {DOFF6, DOFF7, DOFF8, DOFF9, DOFF10, DOFF11};
        int acc = 0;
        for (int s = 0; s < 6; ++s) {
            p6.w[s] = w[6 + s];
            p6.out[s] = wdp + off[s];
            p6.ci[s] = ci[s]; p6.co[s] = co[s];
            p6.start[s] = acc;
            acc += 75 * ci[s] * co[s];
        }
        p6.start[6] = acc;
    }
    wprep2_merged<<<4096, 256, 0, stream>>>(p6);

    hipMemsetAsync(dense0, 0, (size_t)786432 * sizeof(unsigned short), stream);
    hipMemsetAsync(mA, 0, (size_t)262144 * sizeof(float), stream);
    scatter_kernel<<<(npts + 255) / 256, 256, 0, stream>>>(feats, coors, dense0, mA, npts);

    // Level 0 (64^3)
    conv1m_kernel<<<dim3(64, 64), 256, 0, stream>>>(dense0, wv1, mA, ab);
    mfma_conv7<64, 64, 64, 8, 4, 2, 2, 1><<<dim3(8, 64), 512, 0, stream>>>(
        ab, wvp + WOFF0, mA, nullptr, bb);
    pool_bf8(bb, mA, ab, mB, 64, 64, stream);
    // Level 1 (32^3)
    mfma_conv6<64, 96, 32, 2, 1, 2, 3, 1><<<dim3(16, 32), 192, 0, stream>>>(
        ab, wvp + WOFF1, mB, nullptr, bb);
    mfma_conv6<96, 96, 32, 2, 1, 2, 3, 1><<<dim3(16, 32), 192, 0, stream>>>(
        bb, wvp + WOFF2, mB, nullptr, ab);
    pool_bf8(ab, mB, bb, mA, 32, 96, stream);
    // Level 2 (16^3)
    mfma_conv3c<96, 128, 16, 1, 2, 1, 4, 1><<<dim3(16, 16), 256, 0, stream>>>(
        bb, wvp + WOFF3, mA, nullptr, ab);
    mfma_conv3c<128, 128, 16, 1, 2, 1, 4, 1><<<dim3(16, 16), 256, 0, stream>>>(
        ab, wvp + WOFF4, mA, nullptr, bb);
    pool_bf8(bb, mA, ab, mB, 16, 128, stream);
    // Level 3 (8^3)
    dgemm2_kernel<128, 160, 8, 4><<<dim3(32, 10), 256, 0, stream>>>(ab, wdp + DOFF6, mB, bb);
    dgemm2_kernel<160, 160, 8, 4><<<dim3(32, 10), 256, 0, stream>>>(bb, wdp + DOFF7, mB, ab);
    pool_bf8(ab, mB, bb, mA, 8, 160, stream);
    // Level 4 (4^3)
    dgemm2_kernel<160, 192, 4, 8><<<dim3(4, 12), 512, 0, stream>>>(bb, wdp + DOFF8, mA, ab);
    dgemm2_kernel<192, 192, 4, 8><<<dim3(4, 12), 512, 0, stream>>>(ab, wdp + DOFF9, mA, bb);
    pool_bf8(bb, mA, ab, mB, 4, 192, stream);
    // Level 5 (2^3)
    dgemm2_kernel<192, 224, 2, 8><<<dim3(1, 14), 512, 0, stream>>>(ab, wdp + DOFF10, mB, bb);
    dgemm2_kernel<224, 224, 2, 8><<<dim3(1, 14), 512, 0, stream>>>(bb, wdp + DOFF11, mB, ab);
    pool_bf8(ab, mB, bb, mA, 2, 224, stream);
    // Final 1x1x1 convs (center tap only)
    final_kernel<<<1, 256, 0, stream>>>(bb, mA, w[12], w[13], outp);
}

// Round 19
// 699.321 us; speedup vs baseline: 1.0719x; 1.0719x over previous
//
#include <hip/hip_runtime.h>
#include <hip/hip_bf16.h>
#include <cstdint>

typedef __attribute__((ext_vector_type(8))) short bf16x8;
typedef __attribute__((ext_vector_type(4))) float f32x4;

__device__ __forceinline__ unsigned short f2bf_hi(float v) {
    unsigned u = __float_as_uint(v);
    u = u + 0x7fffu + ((u >> 16) & 1u);
    return (unsigned short)(u >> 16);
}
__device__ __forceinline__ float bf2f(unsigned short h) {
    return __uint_as_float(((unsigned)h) << 16);
}

// ---------------------------------------------------------------------------
// scatter: emit bf16 dense directly
__global__ void scatter_kernel(const float* __restrict__ feats,
                               const int* __restrict__ coors,
                               unsigned short* __restrict__ dense,
                               float* __restrict__ mask, int n)
{
    int i = blockIdx.x * blockDim.x + threadIdx.x;
    if (i >= n) return;
    const int z = coors[i * 4 + 1];
    const int y = coors[i * 4 + 2];
    const int x = coors[i * 4 + 3];
    const size_t s = (size_t)((z * 64 + y) * 64 + x);
    dense[s * 3 + 0] = f2bf_hi(feats[i * 3 + 0]);
    dense[s * 3 + 1] = f2bf_hi(feats[i * 3 + 1]);
    dense[s * 3 + 2] = f2bf_hi(feats[i * 3 + 2]);
    mask[s] = 1.f;
}

// ---------------------------------------------------------------------------
// merged weight prep (single-bf16, 5 layers in one launch)
struct Prep5 {
    const float* w[5];
    unsigned short* out[5];
    int ci[5], co[5];
    int start[6];
};
__global__ void wprep_merged(Prep5 P)
{
    const int total = P.start[5];
    const int stride = gridDim.x * blockDim.x;
    for (int g = blockIdx.x * blockDim.x + threadIdx.x; g < total; g += stride) {
        int seg = 0;
        while (g >= P.start[seg + 1]) ++seg;
        const int i = g - P.start[seg];
        const int CI = P.ci[seg], CO = P.co[seg];
        const int tap = i / (CI * CO);
        const int r = i - tap * CI * CO;
        const int ci = r / CO;
        const int co = r - ci * CO;
        const size_t o = ((size_t)(tap * (CI / 8) + (ci >> 3)) * CO + co) * 8 + (ci & 7);
        P.out[seg][o] = f2bf_hi(P.w[seg][i]);
    }
}

// merged weight prep (split hi/lo, 6 deep layers in one launch)
struct Prep6 {
    const float* w[6];
    unsigned short* out[6];
    int ci[6], co[6];
    int start[7];
};
__global__ void wprep2_merged(Prep6 P)
{
    const int total = P.start[6];
    const int stride = gridDim.x * blockDim.x;
    for (int g = blockIdx.x * blockDim.x + threadIdx.x; g < total; g += stride) {
        int seg = 0;
        while (g >= P.start[seg + 1]) ++seg;
        const int i = g - P.start[seg];
        const int CI = P.ci[seg], CO = P.co[seg];
        const int tap = i / (CI * CO);
        const int r = i - tap * CI * CO;
        const int ci = r / CO;
        const int co = r - ci * CO;
        const float v = P.w[seg][i];
        const unsigned short h = f2bf_hi(v);
        const unsigned short l = f2bf_hi(v - bf2f(h));
        const size_t o = ((size_t)(tap * (CI / 8) + (ci >> 3)) * CO + co) * 16 + (ci & 7);
        P.out[seg][o] = h; P.out[seg][o + 8] = l;
    }
}

// conv1 weights: [75][3][64] fp32 -> K=256-padded split hi/lo
__global__ void wprep1_kernel(const float* __restrict__ w,
                              unsigned short* __restrict__ wv1)
{
    const int i = blockIdx.x * blockDim.x + threadIdx.x;
    if (i >= 256 * 64) return;
    const int k = i >> 6, co = i & 63;
    unsigned short h = 0, l = 0;
    if (k < 225) {
        const float v = w[k * 64 + co];
        h = f2bf_hi(v);
        l = f2bf_hi(v - bf2f(h));
    }
    const size_t o = (size_t)(k >> 3) * 1024 + co * 16 + (k & 7);
    wv1[o] = h; wv1[o + 8] = l;
}

// ---------------------------------------------------------------------------
// L0 conv1 via MFMA: per (z,y) row GEMM  M=64(x) x N=64(co) x K=225(pad 256).
__global__ __launch_bounds__(256)
void conv1m_kernel(const unsigned short* __restrict__ in,
                   const unsigned short* __restrict__ wv1,
                   const float* __restrict__ mask, unsigned short* __restrict__ ob)
{
    constexpr int S = 64;
    constexpr int RW = 204;
    constexpr int RP = 208;
    __shared__ unsigned short lds[15 * RP];

    const int bid = blockIdx.y * S + blockIdx.x;
    const int wg = (bid & 7) * (S * S / 8) + (bid >> 3);
    const int y = wg & 63, z = wg >> 6;
    const int t = threadIdx.x;

    for (int idx = t; idx < 15 * RW; idx += 256) {
        const int r = idx / RW;
        const int q = idx - r * RW;
        const int xp = q / 3, ci = q - xp * 3;
        const int kz = r / 5, ky = r - kz * 5;
        const int zz = z + kz - 1, yy = y + ky - 2, xi = xp - 2;
        unsigned short v = 0;
        if ((unsigned)zz < (unsigned)S && (unsigned)yy < (unsigned)S && (unsigned)xi < (unsigned)S)
            v = in[(size_t)((zz * S + yy) * S + xi) * 3 + ci];
        lds[r * RP + q] = v;
    }
    __syncthreads();

    const int lane = t & 63;
    const int xf = t >> 6;
    const int col = lane & 15;
    const int ci8 = lane >> 4;

    f32x4 acc[4];
    const f32x4 vzero = {0.f, 0.f, 0.f, 0.f};
#pragma unroll
    for (int n = 0; n < 4; ++n) acc[n] = vzero;

    const int abase = (xf * 16 + col) * 3;

#pragma unroll
    for (int kc = 0; kc < 8; ++kc) {
        unsigned short av[8];
#pragma unroll
        for (int e = 0; e < 8; ++e) {
            int k = kc * 32 + ci8 * 8 + e;
            if (k > 224) k = 224;
            const int tap = k / 3, ci = k - 3 * tap;
            const int kzy = tap / 5, kx = tap - kzy * 5;
            av[e] = lds[kzy * RP + abase + kx * 3 + ci];
        }
        bf16x8 a;
#pragma unroll
        for (int e = 0; e < 8; ++e) ((unsigned short*)&a)[e] = av[e];

#pragma unroll
        for (int n = 0; n < 4; ++n) {
            const unsigned short* wp = wv1 + (size_t)(kc * 4 + ci8) * 1024 + (n * 16 + col) * 16;
            bf16x8 wh = *(const bf16x8*)wp;
            bf16x8 wl = *(const bf16x8*)(wp + 8);
            acc[n] = __builtin_amdgcn_mfma_f32_16x16x32_bf16(a, wh, acc[n], 0, 0, 0);
            acc[n] = __builtin_amdgcn_mfma_f32_16x16x32_bf16(a, wl, acc[n], 0, 0, 0);
        }
    }

    const int rq = lane >> 4;
    const size_t vb = (size_t)(z * S + y) * S;
#pragma unroll
    for (int r = 0; r < 4; ++r) {
        const int x = xf * 16 + rq * 4 + r;
        const float keep = (mask[vb + x] > 0.f) ? 1.f : 0.f;
#pragma unroll
        for (int n = 0; n < 4; ++n) {
            const int co = n * 16 + col;
            ob[(vb + x) * 64 + co] = f2bf_hi(acc[n][r] * keep);
        }
    }
}

// ---------------------------------------------------------------------------
// MFMA conv v7 (L0c2): YB rows/block, two rows staged per phase.
template<int CIN, int COUT, int S, int YB, int YG, int WN, int NG, int OMODE>
__global__ __launch_bounds__(YG * NG * 64)
void mfma_conv7(const unsigned short* __restrict__ ab,
                const unsigned short* __restrict__ wv,
                const float* __restrict__ mask, float* __restrict__ outf,
                unsigned short* __restrict__ outb)
{
    constexpr int SP = S + 4;
    constexpr int MX = S / 16;
    constexpr int KC = CIN / 32;
    constexpr int KC4 = CIN / 8;
    constexpr int RS = (KC4 <= 8) ? 8 : 16;
    constexpr int PLANE = SP * RS;
    constexpr int NLR = SP * KC4;
    constexpr int NL = 2 * NLR;
    constexpr int NW = YG * NG;
    constexpr int NT = NW * 64;
    constexpr int SREG = (NL + NT - 1) / NT;
    constexpr int YBW = YB / YG;
    constexpr int NYB = S / YB;
    constexpr int JP = (YB + 4) / 2;
    constexpr int NP = 3 * JP;
    static_assert(COUT / 16 == WN * NG, "geometry");
    static_assert((YB + 4) % 2 == 0, "YB even");

    __shared__ unsigned short lds[2 * 2 * PLANE * 8];

    const int bid = blockIdx.y * NYB + blockIdx.x;
    constexpr int NWG = NYB * S;
    const int wg = (bid & 7) * (NWG / 8) + (bid >> 3);
    const int yb = wg % NYB, z = wg / NYB;
    const int y0 = yb * YB;

    const int t = threadIdx.x;
    const int lane = t & 63;
    const int wave = t >> 6;
    const int waveN = wave % NG;
    const int waveY = wave / NG;
    const int col = lane & 15;
    const int ci8 = lane >> 4;

    f32x4 acc[YBW][MX][WN];
    const f32x4 vzero = {0.f, 0.f, 0.f, 0.f};
#pragma unroll
    for (int q = 0; q < YBW; ++q)
#pragma unroll
        for (int m = 0; m < MX; ++m)
#pragma unroll
            for (int n = 0; n < WN; ++n) acc[q][m][n] = vzero;

    uint4 reg[SREG];

    auto issue = [&](int ph) {
        const int kz = ph / JP, jp = ph - kz * JP;
        const int zz = z + kz - 1;
        const bool zv = ((unsigned)zz < (unsigned)S);
#pragma unroll
        for (int i = 0; i < SREG; ++i) {
            const int L = i * NT + t;
            uint4 v = {0u, 0u, 0u, 0u};
            if (L < NL) {
                const int jr = L / NLR;
                const int l2 = L - jr * NLR;
                const int x = l2 / KC4;
                const int c3 = l2 - x * KC4;
                const int xi = x - 2;
                const int yy = y0 + jp * 2 + jr - 2;
                if (zv && (unsigned)yy < (unsigned)S && (unsigned)xi < (unsigned)S)
                    v = *(const uint4*)(ab + (size_t)((zz * S + yy) * S + xi) * CIN + c3 * 8);
            }
            reg[i] = v;
        }
    };
    auto store = [&](int pl) {
#pragma unroll
        for (int i = 0; i < SREG; ++i) {
            const int L = i * NT + t;
            if (L < NL) {
                const int jr = L / NLR;
                const int l2 = L - jr * NLR;
                const int x = l2 / KC4;
                const int c3 = l2 - x * KC4;
                const int p = x * RS + (c3 ^ (x & 7));
                *(uint4*)&lds[((pl * 2 + jr) * PLANE + p) * 8] = reg[i];
            }
        }
    };

    issue(0);
    store(0);
    if (NP > 1) issue(1);
    __syncthreads();

    int cur = 0;
#pragma unroll 1
    for (int ph = 0; ph < NP; ++ph) {
        const int kz = ph / JP, jp = ph - kz * JP;
        const int zz = z + kz - 1;
        if ((unsigned)zz < (unsigned)S) {
#pragma unroll
            for (int jr = 0; jr < 2; ++jr) {
                const int j = jp * 2 + jr;
                const int yy = y0 + j - 2;
                if ((unsigned)yy >= (unsigned)S) continue;
                const unsigned short* plane = lds + (cur * 2 + jr) * PLANE * 8;

                bool vq[YBW];
                int tapb[YBW];
#pragma unroll
                for (int ql = 0; ql < YBW; ++ql) {
                    const int q = waveY * YBW + ql;
                    const int ky = j - q;
                    vq[ql] = (ky >= 0 && ky <= 4);
                    tapb[ql] = (kz * 5 + (vq[ql] ? ky : 0)) * 5;
                }

                bf16x8 wA[YBW][KC][WN], wB[YBW][KC][WN];
                auto wload = [&](bf16x8 (&wb)[YBW][KC][WN], int kx) {
#pragma unroll
                    for (int ql = 0; ql < YBW; ++ql) if (vq[ql]) {
                        const int tap = tapb[ql] + kx;
#pragma unroll
                        for (int kc = 0; kc < KC; ++kc) {
                            const int c3 = kc * 4 + ci8;
#pragma unroll
                            for (int n = 0; n < WN; ++n) {
                                const int co = (waveN * WN + n) * 16 + col;
                                wb[ql][kc][n] = *(const bf16x8*)(wv + ((size_t)(tap * KC4 + c3) * COUT + co) * 8);
                            }
                        }
                    }
                };
                auto wmfma = [&](bf16x8 (&wb)[YBW][KC][WN], bf16x8 (&a)[KC][MX]) {
#pragma unroll
                    for (int ql = 0; ql < YBW; ++ql) if (vq[ql])
#pragma unroll
                        for (int kc = 0; kc < KC; ++kc)
#pragma unroll
                            for (int m = 0; m < MX; ++m)
#pragma unroll
                                for (int n = 0; n < WN; ++n)
                                    acc[ql][m][n] = __builtin_amdgcn_mfma_f32_16x16x32_bf16(a[kc][m], wb[ql][kc][n], acc[ql][m][n], 0, 0, 0);
                };

                wload(wA, 0);
                __builtin_amdgcn_s_setprio(1);
#pragma unroll
                for (int kx = 0; kx < 5; ++kx) {
                    bf16x8 a[KC][MX];
#pragma unroll
                    for (int kc = 0; kc < KC; ++kc) {
                        const int c3 = kc * 4 + ci8;
#pragma unroll
                        for (int m = 0; m < MX; ++m) {
                            const int x = m * 16 + col + kx;
                            const int p = x * RS + (c3 ^ (x & 7));
                            a[kc][m] = *(const bf16x8*)&plane[p * 8];
                        }
                    }
                    if ((kx & 1) == 0) {
                        if (kx + 1 < 5) wload(wB, kx + 1);
                        wmfma(wA, a);
                    } else {
                        if (kx + 1 < 5) wload(wA, kx + 1);
                        wmfma(wB, a);
                    }
                }
                __builtin_amdgcn_s_setprio(0);
            }
        }
        if (ph + 1 < NP) store(cur ^ 1);
        if (ph + 2 < NP) issue(ph + 2);
        __syncthreads();
        cur ^= 1;
    }

    const int rq = lane >> 4;
#pragma unroll
    for (int ql = 0; ql < YBW; ++ql) {
        const int y = y0 + waveY * YBW + ql;
        const size_t vb = (size_t)(z * S + y) * S;
#pragma unroll
        for (int m = 0; m < MX; ++m) {
            const int xb = m * 16 + rq * 4;
#pragma unroll
            for (int r = 0; r < 4; ++r) {
                const int x = xb + r;
                const float keep = (mask[vb + x] > 0.f) ? 1.f : 0.f;
#pragma unroll
                for (int n = 0; n < WN; ++n) {
                    const int co = (waveN * WN + n) * 16 + col;
                    const float v = acc[ql][m][n][r] * keep;
                    if (OMODE == 0) outf[(vb + x) * COUT + co] = v;
                    else            outb[(vb + x) * COUT + co] = f2bf_hi(v);
                }
            }
        }
    }
}

// ---------------------------------------------------------------------------
// MFMA conv v6 (L1): YB rows/block, one row per phase.
template<int CIN, int COUT, int S, int YB, int YG, int WN, int NG, int OMODE>
__global__ __launch_bounds__(YG * NG * 64)
void mfma_conv6(const unsigned short* __restrict__ ab,
                const unsigned short* __restrict__ wv,
                const float* __restrict__ mask, float* __restrict__ outf,
                unsigned short* __restrict__ outb)
{
    constexpr int SP = S + 4;
    constexpr int MX = S / 16;
    constexpr int KC = CIN / 32;
    constexpr int KC4 = CIN / 8;
    constexpr int RS = (KC4 <= 8) ? 8 : 16;
    constexpr int PLANE = SP * RS;
    constexpr int NL = SP * KC4;
    constexpr int NW = YG * NG;
    constexpr int NT = NW * 64;
    constexpr int SREG = (NL + NT - 1) / NT;
    constexpr int YBW = YB / YG;
    constexpr int NYB = S / YB;
    constexpr int NP = 3 * (YB + 4);
    static_assert(COUT / 16 == WN * NG, "geometry");

    __shared__ unsigned short lds[2 * PLANE * 8];

    const int bid = blockIdx.y * NYB + blockIdx.x;
    constexpr int NWG = NYB * S;
    const int wg = (bid & 7) * (NWG / 8) + (bid >> 3);
    const int yb = wg % NYB, z = wg / NYB;
    const int y0 = yb * YB;

    const int t = threadIdx.x;
    const int lane = t & 63;
    const int wave = t >> 6;
    const int waveN = wave % NG;
    const int waveY = wave / NG;
    const int col = lane & 15;
    const int ci8 = lane >> 4;

    f32x4 acc[YBW][MX][WN];
    const f32x4 vzero = {0.f, 0.f, 0.f, 0.f};
#pragma unroll
    for (int q = 0; q < YBW; ++q)
#pragma unroll
        for (int m = 0; m < MX; ++m)
#pragma unroll
            for (int n = 0; n < WN; ++n) acc[q][m][n] = vzero;

    uint4 reg[SREG];

    auto issue = [&](int ph) {
        const int kz = ph / (YB + 4), j = ph - kz * (YB + 4);
        const int zz = z + kz - 1, yy = y0 + j - 2;
        const bool rv = ((unsigned)zz < (unsigned)S) && ((unsigned)yy < (unsigned)S);
        const size_t rowbase = rv ? (size_t)((zz * S + yy) * S) * CIN : 0;
#pragma unroll
        for (int i = 0; i < SREG; ++i) {
            const int L = i * NT + t;
            uint4 v = {0u, 0u, 0u, 0u};
            if (L < NL) {
                const int x = L / KC4;
                const int c3 = L - x * KC4;
                const int xi = x - 2;
                if (rv && (unsigned)xi < (unsigned)S)
                    v = *(const uint4*)(ab + rowbase + (size_t)xi * CIN + c3 * 8);
            }
            reg[i] = v;
        }
    };
    auto store = [&](int pl) {
#pragma unroll
        for (int i = 0; i < SREG; ++i) {
            const int L = i * NT + t;
            if (L < NL) {
                const int x = L / KC4;
                const int c3 = L - x * KC4;
                const int p = x * RS + (c3 ^ (x & 7));
                *(uint4*)&lds[(pl * PLANE + p) * 8] = reg[i];
            }
        }
    };

    issue(0);
    store(0);
    if (NP > 1) issue(1);
    __syncthreads();

    int cur = 0;
#pragma unroll 1
    for (int ph = 0; ph < NP; ++ph) {
        const int kz = ph / (YB + 4), j = ph - kz * (YB + 4);
        const int zz = z + kz - 1, yy = y0 + j - 2;
        if (((unsigned)zz < (unsigned)S) && ((unsigned)yy < (unsigned)S)) {
            const unsigned short* plane = lds + cur * PLANE * 8;

            bool vq[YBW];
            int tapb[YBW];
#pragma unroll
            for (int ql = 0; ql < YBW; ++ql) {
                const int q = waveY * YBW + ql;
                const int ky = j - q;
                vq[ql] = (ky >= 0 && ky <= 4);
                tapb[ql] = (kz * 5 + (vq[ql] ? ky : 0)) * 5;
            }

            bf16x8 wA[YBW][KC][WN], wB[YBW][KC][WN];
            auto wload = [&](bf16x8 (&wb)[YBW][KC][WN], int kx) {
#pragma unroll
                for (int ql = 0; ql < YBW; ++ql) if (vq[ql]) {
                    const int tap = tapb[ql] + kx;
#pragma unroll
                    for (int kc = 0; kc < KC; ++kc) {
                        const int c3 = kc * 4 + ci8;
#pragma unroll
                        for (int n = 0; n < WN; ++n) {
                            const int co = (waveN * WN + n) * 16 + col;
                            wb[ql][kc][n] = *(const bf16x8*)(wv + ((size_t)(tap * KC4 + c3) * COUT + co) * 8);
                        }
                    }
                }
            };
            auto wmfma = [&](bf16x8 (&wb)[YBW][KC][WN], bf16x8 (&a)[KC][MX]) {
#pragma unroll
                for (int ql = 0; ql < YBW; ++ql) if (vq[ql])
#pragma unroll
                    for (int kc = 0; kc < KC; ++kc)
#pragma unroll
                        for (int m = 0; m < MX; ++m)
#pragma unroll
                            for (int n = 0; n < WN; ++n)
                                acc[ql][m][n] = __builtin_amdgcn_mfma_f32_16x16x32_bf16(a[kc][m], wb[ql][kc][n], acc[ql][m][n], 0, 0, 0);
            };

            wload(wA, 0);
            __builtin_amdgcn_s_setprio(1);
#pragma unroll
            for (int kx = 0; kx < 5; ++kx) {
                bf16x8 a[KC][MX];
#pragma unroll
                for (int kc = 0; kc < KC; ++kc) {
                    const int c3 = kc * 4 + ci8;
#pragma unroll
                    for (int m = 0; m < MX; ++m) {
                        const int x = m * 16 + col + kx;
                        const int p = x * RS + (c3 ^ (x & 7));
                        a[kc][m] = *(const bf16x8*)&plane[p * 8];
                    }
                }
                if ((kx & 1) == 0) {
                    if (kx + 1 < 5) wload(wB, kx + 1);
                    wmfma(wA, a);
                } else {
                    if (kx + 1 < 5) wload(wA, kx + 1);
                    wmfma(wB, a);
                }
            }
            __builtin_amdgcn_s_setprio(0);
        }
        if (ph + 1 < NP) store(cur ^ 1);
        if (ph + 2 < NP) issue(ph + 2);
        __syncthreads();
        cur ^= 1;
    }

    const int rq = lane >> 4;
#pragma unroll
    for (int ql = 0; ql < YBW; ++ql) {
        const int y = y0 + waveY * YBW + ql;
        const size_t vb = (size_t)(z * S + y) * S;
#pragma unroll
        for (int m = 0; m < MX; ++m) {
            const int xb = m * 16 + rq * 4;
#pragma unroll
            for (int r = 0; r < 4; ++r) {
                const int x = xb + r;
                const float keep = (mask[vb + x] > 0.f) ? 1.f : 0.f;
#pragma unroll
                for (int n = 0; n < WN; ++n) {
                    const int co = (waveN * WN + n) * 16 + col;
                    const float v = acc[ql][m][n][r] * keep;
                    if (OMODE == 0) outf[(vb + x) * COUT + co] = v;
                    else            outb[(vb + x) * COUT + co] = f2bf_hi(v);
                }
            }
        }
    }
}

// ---------------------------------------------------------------------------
// MFMA conv v3c (L2): single-bf16 weights, LDS double-buffer, kx pipelining.
template<int CIN, int COUT, int S, int WM, int WN, int MG, int NG, int OMODE>
__global__ __launch_bounds__(MG * NG * 64)
void mfma_conv3c(const unsigned short* __restrict__ ab,
                 const unsigned short* __restrict__ wv,
                 const float* __restrict__ mask, float* __restrict__ outf,
                 unsigned short* __restrict__ outb)
{
    constexpr int SP = S + 4;
    constexpr int KC = CIN / 32;
    constexpr int KC4 = CIN / 8;
    constexpr int RS = (KC4 <= 8) ? 8 : 16;
    constexpr int PLANE = SP * RS;
    constexpr int NL = SP * KC4;
    constexpr int NT = MG * NG * 64;
    constexpr int SREG = (NL + NT - 1) / NT;
    static_assert(S / 16 == WM * MG && COUT / 16 == WN * NG, "geometry");

    __shared__ unsigned short lds[2 * PLANE * 8];

    const int bid = blockIdx.y * S + blockIdx.x;
    const int wg = (bid & 7) * (S * S / 8) + (bid >> 3);
    const int y = wg % S, z = wg / S;

    const int t = threadIdx.x;
    const int lane = t & 63;
    const int wave = t >> 6;
    const int waveM = wave % MG;
    const int waveN = wave / MG;
    const int col = lane & 15;
    const int ci8 = lane >> 4;

    f32x4 acc[WM][WN];
    const f32x4 vzero = {0.f, 0.f, 0.f, 0.f};
#pragma unroll
    for (int m = 0; m < WM; ++m)
#pragma unroll
        for (int n = 0; n < WN; ++n) acc[m][n] = vzero;

    uint4 reg[SREG];

    auto issue = [&](int kzy) {
        const int kz = kzy / 5, ky = kzy - kz * 5;
        const int zz = z + kz - 1, yy = y + ky - 2;
        const bool rv = ((unsigned)zz < (unsigned)S) && ((unsigned)yy < (unsigned)S);
        const size_t rowbase = rv ? (size_t)((zz * S + yy) * S) * CIN : 0;
#pragma unroll
        for (int i = 0; i < SREG; ++i) {
            const int L = i * NT + t;
            uint4 v = {0u, 0u, 0u, 0u};
            if (L < NL) {
                const int x = L / KC4;
                const int c3 = L - x * KC4;
                const int xi = x - 2;
                if (rv && (unsigned)xi < (unsigned)S)
                    v = *(const uint4*)(ab + rowbase + (size_t)xi * CIN + c3 * 8);
            }
            reg[i] = v;
        }
    };
    auto store = [&](int pl) {
#pragma unroll
        for (int i = 0; i < SREG; ++i) {
            const int L = i * NT + t;
            if (L < NL) {
                const int x = L / KC4;
                const int c3 = L - x * KC4;
                const int p = x * RS + (c3 ^ (x & 7));
                *(uint4*)&lds[(pl * PLANE + p) * 8] = reg[i];
            }
        }
    };

    issue(0);
    store(0);
    issue(1);
    __syncthreads();

    int cur = 0;
#pragma unroll 1
    for (int kzy = 0; kzy < 15; ++kzy) {
        const int kz = kzy / 5, ky = kzy - kz * 5;
        const int zz = z + kz - 1, yy = y + ky - 2;
        if (((unsigned)zz < (unsigned)S) && ((unsigned)yy < (unsigned)S)) {
            const unsigned short* plane = lds + cur * PLANE * 8;

            bf16x8 wA[KC][WN], wB[KC][WN];
            auto wload = [&](bf16x8 (&wb)[KC][WN], int kx) {
                const int tap = kzy * 5 + kx;
#pragma unroll
                for (int kc = 0; kc < KC; ++kc) {
                    const int c3 = kc * 4 + ci8;
#pragma unroll
                    for (int n = 0; n < WN; ++n) {
                        const int co = (waveN * WN + n) * 16 + col;
                        wb[kc][n] = *(const bf16x8*)(wv + ((size_t)(tap * KC4 + c3) * COUT + co) * 8);
                    }
                }
            };
            auto wmfma = [&](bf16x8 (&wb)[KC][WN], bf16x8 (&a)[KC][WM]) {
#pragma unroll
                for (int kc = 0; kc < KC; ++kc)
#pragma unroll
                    for (int m = 0; m < WM; ++m)
#pragma unroll
                        for (int n = 0; n < WN; ++n)
                            acc[m][n] = __builtin_amdgcn_mfma_f32_16x16x32_bf16(a[kc][m], wb[kc][n], acc[m][n], 0, 0, 0);
            };

            wload(wA, 0);
            __builtin_amdgcn_s_setprio(1);
#pragma unroll
            for (int kx = 0; kx < 5; ++kx) {
                bf16x8 a[KC][WM];
#pragma unroll
                for (int kc = 0; kc < KC; ++kc) {
                    const int c3 = kc * 4 + ci8;
#pragma unroll
                    for (int m = 0; m < WM; ++m) {
                        const int x = (waveM * WM + m) * 16 + col + kx;
                        const int p = x * RS + (c3 ^ (x & 7));
                        a[kc][m] = *(const bf16x8*)&plane[p * 8];
                    }
                }
                if ((kx & 1) == 0) {
                    if (kx + 1 < 5) wload(wB, kx + 1);
                    wmfma(wA, a);
                } else {
                    if (kx + 1 < 5) wload(wA, kx + 1);
                    wmfma(wB, a);
                }
            }
            __builtin_amdgcn_s_setprio(0);
        }
        if (kzy + 1 < 15) store(cur ^ 1);
        if (kzy + 2 < 15) issue(kzy + 2);
        __syncthreads();
        cur ^= 1;
    }

    const int rq = lane >> 4;
    const size_t vb = (size_t)(z * S + y) * S;
#pragma unroll
    for (int m = 0; m < WM; ++m) {
        const int xb = (waveM * WM + m) * 16 + rq * 4;
#pragma unroll
        for (int r = 0; r < 4; ++r) {
            const int x = xb + r;
            const float keep = (mask[vb + x] > 0.f) ? 1.f : 0.f;
#pragma unroll
            for (int n = 0; n < WN; ++n) {
                const int co = (waveN * WN + n) * 16 + col;
                const float v = acc[m][n][r] * keep;
                if (OMODE == 0) outf[(vb + x) * COUT + co] = v;
                else            outb[(vb + x) * COUT + co] = f2bf_hi(v);
            }
        }
    }
}

// ---------------------------------------------------------------------------
// Deep-level conv as flat implicit GEMM v2: NW waves split the 75 taps.
template<int CIN, int COUT, int S, int NW>
__global__ __launch_bounds__(NW * 64)
void dgemm2_kernel(const unsigned short* __restrict__ inb,
                   const unsigned short* __restrict__ wv,
                   const float* __restrict__ mask,
                   unsigned short* __restrict__ outb)
{
    constexpr int M = S * S * S;
    constexpr int KC = CIN / 32;
    constexpr int KC4 = CIN / 8;
    __shared__ f32x4 part[NW][64];

    const int t = threadIdx.x;
    const int lane = t & 63;
    const int w = t >> 6;
    const int col = lane & 15;
    const int g = lane >> 4;

    const int va = blockIdx.x * 16 + col;
    const bool av = (va < M);
    const int az = (va / (S * S)) % S;
    const int ay = (va / S) % S;
    const int ax = va % S;
    const int co = blockIdx.y * 16 + col;

    f32x4 acc0 = {0.f, 0.f, 0.f, 0.f};
    f32x4 acc1 = {0.f, 0.f, 0.f, 0.f};

#pragma unroll 2
    for (int tap = w; tap < 75; tap += NW) {
        const int dz = tap / 25 - 1;
        const int dy = (tap / 5) % 5 - 2;
        const int dx = tap % 5 - 2;
        const int zz = az + dz, yy = ay + dy, xx = ax + dx;
        const bool valid = av && ((unsigned)zz < (unsigned)S) &&
                           ((unsigned)yy < (unsigned)S) && ((unsigned)xx < (unsigned)S);
        const size_t abase = valid ? (size_t)((zz * S + yy) * S + xx) * CIN : 0;
#pragma unroll
        for (int kc = 0; kc < KC; ++kc) {
            const int c3 = kc * 4 + g;
            bf16x8 a = {0, 0, 0, 0, 0, 0, 0, 0};
            if (valid) a = *(const bf16x8*)(inb + abase + c3 * 8);
            const unsigned short* wp = wv + ((size_t)(tap * KC4 + c3) * COUT + co) * 16;
            bf16x8 wh = *(const bf16x8*)wp;
            bf16x8 wl = *(const bf16x8*)(wp + 8);
            acc0 = __builtin_amdgcn_mfma_f32_16x16x32_bf16(a, wh, acc0, 0, 0, 0);
            acc1 = __builtin_amdgcn_mfma_f32_16x16x32_bf16(a, wl, acc1, 0, 0, 0);
        }
    }

    part[w][lane] = acc0 + acc1;
    __syncthreads();

    if (w == 0) {
        f32x4 s = part[0][lane];
#pragma unroll
        for (int i = 1; i < NW; ++i) s += part[i][lane];
#pragma unroll
        for (int r = 0; r < 4; ++r) {
            const int v = blockIdx.x * 16 + g * 4 + r;
            if (v < M) {
                const float keep = (mask[v] > 0.f) ? 1.f : 0.f;
                outb[(size_t)v * COUT + co] = f2bf_hi(s[r] * keep);
            }
        }
    }
}

// ---------------------------------------------------------------------------
// bf16 pool, vectorized: 8 channels per thread.
__global__ void pool_bf8_kernel(const unsigned short* __restrict__ inb,
                                const float* __restrict__ mi,
                                unsigned short* __restrict__ outb,
                                float* __restrict__ mo, int S, int C)
{
    const int So = S >> 1;
    const int C8 = C >> 3;
    const long long total = (long long)So * So * So * C8;
    for (long long i = blockIdx.x * (long long)blockDim.x + threadIdx.x; i < total;
         i += (long long)gridDim.x * blockDim.x) {
        const int c8 = (int)(i % C8);
        const long long s = i / C8;
        const int xo = (int)(s % So);
        const int yo = (int)((s / So) % So);
        const int zo = (int)(s / ((long long)So * So));
        float best[8];
#pragma unroll
        for (int k = 0; k < 8; ++k) best[k] = -1e30f;
        float m2 = 0.f;
        for (int dz = 0; dz < 2; ++dz)
            for (int dy = 0; dy < 2; ++dy)
                for (int dx = 0; dx < 2; ++dx) {
                    const int zi = zo * 2 + dz, yi = yo * 2 + dy, xi = xo * 2 + dx;
                    const float m = mi[(zi * S + yi) * S + xi];
                    if (m > 0.f) {
                        m2 = 1.f;
                        const unsigned short* p =
                            inb + ((size_t)((zi * S + yi) * S + xi) * C8 + c8) * 8;
                        uint4 v = *(const uint4*)p;
                        const unsigned short* vs = (const unsigned short*)&v;
#pragma unroll
                        for (int k = 0; k < 8; ++k) best[k] = fmaxf(best[k], bf2f(vs[k]));
                    }
                }
        uint4 o;
        unsigned short* os = (unsigned short*)&o;
#pragma unroll
        for (int k = 0; k < 8; ++k) os[k] = f2bf_hi((m2 > 0.f) ? best[k] : 0.f);
        *(uint4*)(outb + i * 8) = o;
        if (c8 == 0) mo[s] = m2;
    }
}

__global__ __launch_bounds__(256)
void final_kernel(const unsigned short* __restrict__ h, const float* __restrict__ mask,
                  const float* __restrict__ w12, const float* __restrict__ w13,
                  float* __restrict__ out)
{
    __shared__ float o1[256];
    const int co = threadIdx.x;
    const float m = (mask[0] > 0.f) ? 1.f : 0.f;
    float a = 0.f;
    for (int ci = 0; ci < 224; ++ci)
        a += bf2f(h[ci]) * w12[(size_t)(37 * 224 + ci) * 256 + co];
    o1[co] = a * m;
    __syncthreads();
    float b = 0.f;
    for (int ci = 0; ci < 256; ++ci)
        b += o1[ci] * w13[(size_t)(37 * 256 + ci) * 256 + co];
    out[co] = b * m;
}

static void pool_bf8(const unsigned short* inb, const float* mi,
                     unsigned short* outb, float* mo, int S, int C, hipStream_t stream)
{
    const long long total = (long long)(S / 2) * (S / 2) * (S / 2) * (C / 8);
    long long grid = (total + 255) / 256;
    if (grid > 4096) grid = 4096;
    if (grid < 1) grid = 1;
    pool_bf8_kernel<<<(int)grid, 256, 0, stream>>>(inb, mi, outb, mo, S, C);
}

// weight-pool element offsets (shorts, hi-only): L0c2, L1c1, L1c2, L2c1, L2c2
#define WOFF0 0
#define WOFF1 307200
#define WOFF2 768000
#define WOFF3 1459200
#define WOFF4 2380800
// deep split-weight offsets (shorts, hi+lo): L3c1..L5c2
#define DOFF6 0
#define DOFF7 3072000
#define DOFF8 6912000
#define DOFF9 11520000
#define DOFF10 17049600
#define DOFF11 23500800

extern "C" void kernel_launch(void* const* d_in, const int* in_sizes, int n_in,
                              void* d_out, int out_size, void* d_ws, size_t ws_size,
                              hipStream_t stream)
{
    const float* feats = (const float*)d_in[0];
    const int*   coors = (const int*)d_in[1];
    const float* w[14];
    for (int i = 0; i < 14; ++i) w[i] = (const float*)d_in[3 + i];
    float* outp = (float*)d_out;

    // ws layout
    unsigned short* dense0 = (unsigned short*)d_ws;        // bf16, 786432 shorts
    float* mA = (float*)d_ws + 786432;                     // 262144
    float* mB = mA + 262144;                               // 262144
    unsigned short* ab = (unsigned short*)(mB + 262144);   // 16.7M shorts
    unsigned short* bb = ab + 16777216;                    // 16.7M shorts
    unsigned short* wvp = bb + 16777216;                   // 3.6M shorts (L0-L2)
    unsigned short* wdp = wvp + 3609600;                   // 31.1M shorts (deep)
    unsigned short* wv1 = wdp + 31104000;                  // 32768 shorts (conv1)

    const int npts = in_sizes[0] / 3;

    // ---- weight prep: 3 launches total ----
    wprep1_kernel<<<64, 256, 0, stream>>>(w[0], wv1);

    Prep5 p5;
    {
        const int ci[5] = {64, 64, 96, 96, 128};
        const int co[5] = {64, 96, 96, 128, 128};
        const int off[5] = {WOFF0, WOFF1, WOFF2, WOFF3, WOFF4};
        int acc = 0;
        for (int s = 0; s < 5; ++s) {
            p5.w[s] = w[1 + s];
            p5.out[s] = wvp + off[s];
            p5.ci[s] = ci[s]; p5.co[s] = co[s];
            p5.start[s] = acc;
            acc += 75 * ci[s] * co[s];
        }
        p5.start[5] = acc;
    }
    wprep_merged<<<2048, 256, 0, stream>>>(p5);

    Prep6 p6;
    {
        const int ci[6] = {128, 160, 160, 192, 192, 224};
        const int co[6] = {160, 160, 192, 192, 224, 224};
        const int off[6] = {DOFF6, DOFF7, DOFF8, DOFF9, DOFF10, DOFF11};
        int acc = 0;
        for (int s = 0; s < 6; ++s) {
            p6.w[s] = w[6 + s];
            p6.out[s] = wdp + off[s];
            p6.ci[s] = ci[s]; p6.co[s] = co[s];
            p6.start[s] = acc;
            acc += 75 * ci[s] * co[s];
        }
        p6.start[6] = acc;
    }
    wprep2_merged<<<4096, 256, 0, stream>>>(p6);

    hipMemsetAsync(dense0, 0, (size_t)786432 * sizeof(unsigned short), stream);
    hipMemsetAsync(mA, 0, (size_t)262144 * sizeof(float), stream);
    scatter_kernel<<<(npts + 255) / 256, 256, 0, stream>>>(feats, coors, dense0, mA, npts);

    // Level 0 (64^3)  — L0c2 restored to round-17 known-good YB=4/YG=2
    conv1m_kernel<<<dim3(64, 64), 256, 0, stream>>>(dense0, wv1, mA, ab);
    mfma_conv7<64, 64, 64, 4, 2, 2, 2, 1><<<dim3(16, 64), 256, 0, stream>>>(
        ab, wvp + WOFF0, mA, nullptr, bb);
    pool_bf8(bb, mA, ab, mB, 64, 64, stream);
    // Level 1 (32^3)
    mfma_conv6<64, 96, 32, 2, 1, 2, 3, 1><<<dim3(16, 32), 192, 0, stream>>>(
        ab, wvp + WOFF1, mB, nullptr, bb);
    mfma_conv6<96, 96, 32, 2, 1, 2, 3, 1><<<dim3(16, 32), 192, 0, stream>>>(
        bb, wvp + WOFF2, mB, nullptr, ab);
    pool_bf8(ab, mB, bb, mA, 32, 96, stream);
    // Level 2 (16^3)
    mfma_conv3c<96, 128, 16, 1, 2, 1, 4, 1><<<dim3(16, 16), 256, 0, stream>>>(
        bb, wvp + WOFF3, mA, nullptr, ab);
    mfma_conv3c<128, 128, 16, 1, 2, 1, 4, 1><<<dim3(16, 16), 256, 0, stream>>>(
        ab, wvp + WOFF4, mA, nullptr, bb);
    pool_bf8(bb, mA, ab, mB, 16, 128, stream);
    // Level 3 (8^3)
    dgemm2_kernel<128, 160, 8, 4><<<dim3(32, 10), 256, 0, stream>>>(ab, wdp + DOFF6, mB, bb);
    dgemm2_kernel<160, 160, 8, 4><<<dim3(32, 10), 256, 0, stream>>>(bb, wdp + DOFF7, mB, ab);
    pool_bf8(ab, mB, bb, mA, 8, 160, stream);
    // Level 4 (4^3)
    dgemm2_kernel<160, 192, 4, 8><<<dim3(4, 12), 512, 0, stream>>>(bb, wdp + DOFF8, mA, ab);
    dgemm2_kernel<192, 192, 4, 8><<<dim3(4, 12), 512, 0, stream>>>(ab, wdp + DOFF9, mA, bb);
    pool_bf8(bb, mA, ab, mB, 4, 192, stream);
    // Level 5 (2^3)
    dgemm2_kernel<192, 224, 2, 8><<<dim3(1, 14), 512, 0, stream>>>(ab, wdp + DOFF10, mB, bb);
    dgemm2_kernel<224, 224, 2, 8><<<dim3(1, 14), 512, 0, stream>>>(bb, wdp + DOFF11, mB, ab);
    pool_bf8(ab, mB, bb, mA, 2, 224, stream);
    // Final 1x1x1 convs (center tap only)
    final_kernel<<<1, 256, 0, stream>>>(bb, mA, w[12], w[13], outp);
}